// Round 1
// baseline (1495.924 us; speedup 1.0000x reference)
//
#include <hip/hip_runtime.h>
#include <stdint.h>
#include <stddef.h>

// ---------- types & helpers ----------
typedef __bf16 bf16x8 __attribute__((ext_vector_type(8)));
typedef float  f32x4  __attribute__((ext_vector_type(4)));

static __device__ __forceinline__ float bf2f(unsigned short u) {
    union { unsigned int i; float f; } v; v.i = ((unsigned int)u) << 16; return v.f;
}
static __device__ __forceinline__ unsigned short f2bf(float f) {
    union { float f; unsigned int i; } v; v.f = f;
    unsigned int r = v.i + 0x7FFFu + ((v.i >> 16) & 1u);
    return (unsigned short)(r >> 16);
}

#define N_NODES 100000
#define N_EDGES 3200000
#define MPAD    100096   // multiple of 128

// ---------- CSR build ----------
__global__ __launch_bounds__(256) void hist_k(const int* __restrict__ er, int* __restrict__ cnt, int E) {
    int i = blockIdx.x * 256 + threadIdx.x;
    if (i < E) atomicAdd(&cnt[er[i]], 1);
}

__global__ __launch_bounds__(1024) void scan_k(const int* __restrict__ cnt, int* __restrict__ rp, int N, int E) {
    __shared__ int sums[1024];
    int tid = threadIdx.x;
    int chunk = (N + 1023) >> 10;           // 98
    int lo = tid * chunk;
    int hi = lo + chunk; if (hi > N) hi = N;
    int s = 0;
    for (int i = lo; i < hi; i++) s += cnt[i];
    sums[tid] = s;
    __syncthreads();
    for (int off = 1; off < 1024; off <<= 1) {
        int v = (tid >= off) ? sums[tid - off] : 0;
        __syncthreads();
        sums[tid] += v;
        __syncthreads();
    }
    int run = (tid == 0) ? 0 : sums[tid - 1];
    for (int i = lo; i < hi; i++) { rp[i] = run; run += cnt[i]; }
    if (tid == 0) rp[N] = E;
}

__global__ __launch_bounds__(256) void copy_k(const int* __restrict__ rp, int* __restrict__ cur, int N) {
    int i = blockIdx.x * 256 + threadIdx.x;
    if (i < N) cur[i] = rp[i];
}

__global__ __launch_bounds__(256) void scatter_k(const int* __restrict__ er, const int* __restrict__ ec,
                                                 const float* __restrict__ ev, int* __restrict__ cur,
                                                 int* __restrict__ ccol, float* __restrict__ cval, int E) {
    int i = blockIdx.x * 256 + threadIdx.x;
    if (i < E) {
        int r = er[i];
        int p = atomicAdd(&cur[r], 1);
        ccol[p] = ec[i];
        cval[p] = ev[i];
    }
}

// ---------- weight transpose + bf16 convert:  W[K][Nc] -> Wt[Nc][K] ----------
__global__ __launch_bounds__(256) void transpose_k(const float* __restrict__ W, unsigned short* __restrict__ Wt,
                                                   int K, int Nc) {
    int i = blockIdx.x * 256 + threadIdx.x;
    if (i < K * Nc) {
        int k = i / Nc, n = i % Nc;
        Wt[(size_t)n * K + k] = f2bf(W[i]);
    }
}

// ---------- MFMA GEMM: C[Mpad][Nc](bf16) = A[Mpad][K] @ Bt[Nc][K]^T ----------
// A is fp32 (A_F32=true, rows clamped to Mclamp) or bf16 (our padded buffer).
template<int BM, int BN, int BK, bool A_F32>
__global__ __launch_bounds__(256) void gemm_mfma(const void* __restrict__ Aptr,
                                                 const unsigned short* __restrict__ Bt,
                                                 unsigned short* __restrict__ C,
                                                 int K, int Nc, int Mclamp) {
    constexpr int WROWS = 2, WCOLS = 2;
    constexpr int WM = BM / WROWS, WN = BN / WCOLS;
    constexpr int MT = WM / 16, NT = WN / 16;
    constexpr int LDA = BK + 8;             // elems; row stride = (BK+8)*2 bytes, multiple of 16
    constexpr int KV = BK / 8;

    __shared__ unsigned short lds_a[BM * LDA];
    __shared__ unsigned short lds_b[BN * LDA];

    const int tid  = threadIdx.x;
    const int wid  = tid >> 6, lane = tid & 63;
    const int wrow = wid >> 1, wcol = wid & 1;
    const int bm = blockIdx.x * BM, bn = blockIdx.y * BN;
    const int r = lane & 15, q = lane >> 4;

    const float*          Af = (const float*)Aptr;
    const unsigned short* Ab = (const unsigned short*)Aptr;

    f32x4 acc[MT][NT];
    f32x4 zero = {0.f, 0.f, 0.f, 0.f};
#pragma unroll
    for (int mi = 0; mi < MT; mi++)
#pragma unroll
        for (int ni = 0; ni < NT; ni++) acc[mi][ni] = zero;

    for (int k0 = 0; k0 < K; k0 += BK) {
        // stage A tile (BM x BK) as bf16
#pragma unroll
        for (int it = 0; it < (BM * KV) / 256; it++) {
            int v = tid + it * 256;
            int row = v / KV, kc = (v % KV) * 8;
            int grow = bm + row;
            uint4 d;
            if constexpr (A_F32) {
                grow = (grow <= Mclamp) ? grow : Mclamp;
                const float4* pp = (const float4*)(Af + (size_t)grow * K + k0 + kc);
                float4 f0 = pp[0], f1 = pp[1];
                d.x = (unsigned)f2bf(f0.x) | ((unsigned)f2bf(f0.y) << 16);
                d.y = (unsigned)f2bf(f0.z) | ((unsigned)f2bf(f0.w) << 16);
                d.z = (unsigned)f2bf(f1.x) | ((unsigned)f2bf(f1.y) << 16);
                d.w = (unsigned)f2bf(f1.z) | ((unsigned)f2bf(f1.w) << 16);
            } else {
                d = *(const uint4*)(Ab + (size_t)grow * K + k0 + kc);
            }
            *(uint4*)&lds_a[row * LDA + kc] = d;
        }
        // stage Bt tile (BN x BK), already bf16 row-major [Nc][K]
#pragma unroll
        for (int it = 0; it < (BN * KV) / 256; it++) {
            int v = tid + it * 256;
            int row = v / KV, kc = (v % KV) * 8;
            uint4 d = *(const uint4*)(Bt + (size_t)(bn + row) * K + k0 + kc);
            *(uint4*)&lds_b[row * LDA + kc] = d;
        }
        __syncthreads();

#pragma unroll
        for (int kk = 0; kk < BK; kk += 32) {
            bf16x8 av[MT], bv[NT];
#pragma unroll
            for (int mi = 0; mi < MT; mi++)
                av[mi] = *(const bf16x8*)&lds_a[(wrow * WM + mi * 16 + r) * LDA + kk + q * 8];
#pragma unroll
            for (int ni = 0; ni < NT; ni++)
                bv[ni] = *(const bf16x8*)&lds_b[(wcol * WN + ni * 16 + r) * LDA + kk + q * 8];
#pragma unroll
            for (int mi = 0; mi < MT; mi++)
#pragma unroll
                for (int ni = 0; ni < NT; ni++)
                    acc[mi][ni] = __builtin_amdgcn_mfma_f32_16x16x32_bf16(av[mi], bv[ni], acc[mi][ni], 0, 0, 0);
        }
        __syncthreads();
    }

    // epilogue: C/D layout col = lane&15, row = q*4 + d  (m89/m91-verified)
#pragma unroll
    for (int mi = 0; mi < MT; mi++) {
        int row = bm + wrow * WM + mi * 16 + q * 4;
#pragma unroll
        for (int ni = 0; ni < NT; ni++) {
            int cc = bn + wcol * WN + ni * 16 + r;
#pragma unroll
            for (int d = 0; d < 4; d++)
                C[(size_t)(row + d) * Nc + cc] = f2bf(acc[mi][ni][d]);
        }
    }
}

// ---------- SPMM (F=256): one wave per row, lane owns 4 features ----------
__global__ __launch_bounds__(256) void spmm_f256(const int* __restrict__ rp, const int* __restrict__ cols,
                                                 const float* __restrict__ vals, const unsigned short* __restrict__ Z,
                                                 const float* __restrict__ bias, unsigned short* __restrict__ H, int N) {
    int w = (blockIdx.x * 256 + threadIdx.x) >> 6;
    if (w >= N) return;
    int lane = threadIdx.x & 63;
    int f0 = lane * 4;
    int s = rp[w], e = rp[w + 1];
    float a0 = 0.f, a1 = 0.f, a2 = 0.f, a3 = 0.f;
    int j = s;
    for (; j + 2 <= e; j += 2) {
        int   c0 = cols[j],   c1 = cols[j + 1];
        float w0 = vals[j],   w1 = vals[j + 1];
        ushort4 z0 = *(const ushort4*)(Z + (size_t)c0 * 256 + f0);
        ushort4 z1 = *(const ushort4*)(Z + (size_t)c1 * 256 + f0);
        a0 += w0 * bf2f(z0.x); a1 += w0 * bf2f(z0.y); a2 += w0 * bf2f(z0.z); a3 += w0 * bf2f(z0.w);
        a0 += w1 * bf2f(z1.x); a1 += w1 * bf2f(z1.y); a2 += w1 * bf2f(z1.z); a3 += w1 * bf2f(z1.w);
    }
    if (j < e) {
        int c0 = cols[j]; float w0 = vals[j];
        ushort4 z0 = *(const ushort4*)(Z + (size_t)c0 * 256 + f0);
        a0 += w0 * bf2f(z0.x); a1 += w0 * bf2f(z0.y); a2 += w0 * bf2f(z0.z); a3 += w0 * bf2f(z0.w);
    }
    float4 b = *(const float4*)(bias + f0);
    a0 = fmaxf(a0 + b.x, 0.f); a1 = fmaxf(a1 + b.y, 0.f);
    a2 = fmaxf(a2 + b.z, 0.f); a3 = fmaxf(a3 + b.w, 0.f);
    ushort4 o; o.x = f2bf(a0); o.y = f2bf(a1); o.z = f2bf(a2); o.w = f2bf(a3);
    *(ushort4*)(H + (size_t)w * 256 + f0) = o;
}

// ---------- SPMM (F=64) + bias + log_softmax fused ----------
__global__ __launch_bounds__(256) void spmm_f64_lsm(const int* __restrict__ rp, const int* __restrict__ cols,
                                                    const float* __restrict__ vals, const unsigned short* __restrict__ Z,
                                                    const float* __restrict__ bias, float* __restrict__ out, int N) {
    int w = (blockIdx.x * 256 + threadIdx.x) >> 6;
    if (w >= N) return;
    int lane = threadIdx.x & 63;
    int s = rp[w], e = rp[w + 1];
    float a = 0.f;
    int j = s;
    for (; j + 2 <= e; j += 2) {
        int   c0 = cols[j],   c1 = cols[j + 1];
        float w0 = vals[j],   w1 = vals[j + 1];
        float z0 = bf2f(Z[(size_t)c0 * 64 + lane]);
        float z1 = bf2f(Z[(size_t)c1 * 64 + lane]);
        a += w0 * z0 + w1 * z1;
    }
    if (j < e) a += vals[j] * bf2f(Z[(size_t)cols[j] * 64 + lane]);
    a += bias[lane];
    float m = a;
    for (int off = 32; off >= 1; off >>= 1) m = fmaxf(m, __shfl_xor(m, off, 64));
    float ex = __expf(a - m);
    float sum = ex;
    for (int off = 32; off >= 1; off >>= 1) sum += __shfl_xor(sum, off, 64);
    out[(size_t)w * 64 + lane] = a - m - __logf(sum);
}

// ---------- launch ----------
extern "C" void kernel_launch(void* const* d_in, const int* in_sizes, int n_in,
                              void* d_out, int out_size, void* d_ws, size_t ws_size,
                              hipStream_t stream) {
    const float* x  = (const float*)d_in[0];
    const int*   er = (const int*)  d_in[1];
    const int*   ec = (const int*)  d_in[2];
    const float* ev = (const float*)d_in[3];
    const float* W1 = (const float*)d_in[4];
    const float* b1 = (const float*)d_in[5];
    const float* W2 = (const float*)d_in[6];
    const float* b2 = (const float*)d_in[7];
    const float* W3 = (const float*)d_in[8];
    const float* b3 = (const float*)d_in[9];

    const int N = N_NODES, E = N_EDGES;

    char* p = (char*)d_ws;
    auto alloc = [&](size_t bytes) -> char* {
        char* q = p; p += (bytes + 255) & ~(size_t)255; return q;
    };
    unsigned short* Wt1  = (unsigned short*)alloc((size_t)256 * 512 * 2);
    unsigned short* Wt2  = (unsigned short*)alloc((size_t)256 * 256 * 2);
    unsigned short* Wt3  = (unsigned short*)alloc((size_t)64  * 256 * 2);
    int*            rp   = (int*)  alloc((size_t)(N + 1) * 4);
    int*            cnt  = (int*)  alloc((size_t)N * 4);
    int*            cur  = (int*)  alloc((size_t)N * 4);
    int*            ccol = (int*)  alloc((size_t)E * 4);
    float*          cval = (float*)alloc((size_t)E * 4);
    unsigned short* bufA = (unsigned short*)alloc((size_t)MPAD * 256 * 2);
    unsigned short* bufB = (unsigned short*)alloc((size_t)MPAD * 256 * 2);

    // CSR build
    hipMemsetAsync(cnt, 0, (size_t)N * 4, stream);
    hist_k   <<<(E + 255) / 256, 256, 0, stream>>>(er, cnt, E);
    scan_k   <<<1, 1024, 0, stream>>>(cnt, rp, N, E);
    copy_k   <<<(N + 255) / 256, 256, 0, stream>>>(rp, cur, N);
    scatter_k<<<(E + 255) / 256, 256, 0, stream>>>(er, ec, ev, cur, ccol, cval, E);

    // weights -> bf16 transposed
    transpose_k<<<(512 * 256) / 256, 256, 0, stream>>>(W1, Wt1, 512, 256);
    transpose_k<<<(256 * 256) / 256, 256, 0, stream>>>(W2, Wt2, 256, 256);
    transpose_k<<<(256 * 64)  / 256, 256, 0, stream>>>(W3, Wt3, 256, 64);

    // layer 1: Z = x @ W1 ; H = relu(spmm(Z) + b1)
    gemm_mfma<64, 256, 64, true ><<<dim3(MPAD / 64, 1), 256, 0, stream>>>(x,    Wt1, bufA, 512, 256, N - 1);
    spmm_f256<<<N / 4, 256, 0, stream>>>(rp, ccol, cval, bufA, b1, bufB, N);
    // layer 2
    gemm_mfma<64, 256, 64, false><<<dim3(MPAD / 64, 1), 256, 0, stream>>>(bufB, Wt2, bufA, 256, 256, N - 1);
    spmm_f256<<<N / 4, 256, 0, stream>>>(rp, ccol, cval, bufA, b2, bufB, N);
    // layer 3 (+ fused bias + log_softmax)
    gemm_mfma<128, 64, 64, false><<<dim3(MPAD / 128, 1), 256, 0, stream>>>(bufB, Wt3, bufA, 256, 64, N - 1);
    spmm_f64_lsm<<<N / 4, 256, 0, stream>>>(rp, ccol, cval, bufA, b3, (float*)d_out, N);
}